// Round 6
// baseline (644.393 us; speedup 1.0000x reference)
//
#include <hip/hip_runtime.h>
#include <hip/hip_bf16.h>

#define NEG_SLOPE 0.01f
#define BN_EPS 1e-5f
#define POOL_S 16

typedef __attribute__((ext_vector_type(8))) short short8;
typedef __attribute__((ext_vector_type(4))) float f32x4;

__device__ __forceinline__ float bf2f(unsigned short b) {
    unsigned int u = ((unsigned int)b) << 16;
    float f; __builtin_memcpy(&f, &u, 4); return f;
}
__device__ __forceinline__ unsigned short f2bf(float f) {
    unsigned int u; __builtin_memcpy(&u, &f, 4);
    u = (u + 0x7FFFu + ((u >> 16) & 1u)) >> 16;
    return (unsigned short)u;
}

__device__ __forceinline__ void gload_lds16(const void* g, void* l) {
    __builtin_amdgcn_global_load_lds(
        (const __attribute__((address_space(1))) void*)g,
        (__attribute__((address_space(3))) void*)l, 16, 0, 0);
}

// ---------------- x fp32 -> bf16 ----------------
__global__ void k_cvt(const float* __restrict__ x, unsigned short* __restrict__ xb, int total8) {
    int i = blockIdx.x * blockDim.x + threadIdx.x;
    if (i < total8) {
        float4 a = ((const float4*)x)[i * 2];
        float4 b = ((const float4*)x)[i * 2 + 1];
        short8 o;
        o[0] = (short)f2bf(a.x); o[1] = (short)f2bf(a.y);
        o[2] = (short)f2bf(a.z); o[3] = (short)f2bf(a.w);
        o[4] = (short)f2bf(b.x); o[5] = (short)f2bf(b.y);
        o[6] = (short)f2bf(b.z); o[7] = (short)f2bf(b.w);
        ((short8*)xb)[i] = o;
    }
}

// ---------------- CSR build ----------------
__global__ void k_count(const int* __restrict__ ei, int* __restrict__ cnt, int E) {
    int e = blockIdx.x * blockDim.x + threadIdx.x;
    if (e < E) atomicAdd(&cnt[ei[E + e]], 1);
}

__global__ void k_deg(const int* __restrict__ cnt, float* __restrict__ dinv,
                      float* __restrict__ self_norm, int N) {
    int n = blockIdx.x * blockDim.x + threadIdx.x;
    if (n < N) {
        float deg = (float)(cnt[n] + 1);
        dinv[n] = rsqrtf(deg);
        self_norm[n] = 1.0f / deg;
    }
}

__global__ void k_scan(const int* __restrict__ cnt, int* __restrict__ row_ptr, int n) {
    __shared__ int wsum[16];
    __shared__ int carry_s;
    int tid = threadIdx.x;
    int lane = tid & 63, wid = tid >> 6;
    if (tid == 0) carry_s = 0;
    __syncthreads();
    for (int base = 0; base < n; base += 1024) {
        int i = base + tid;
        int v = (i < n) ? cnt[i] : 0;
        int x = v;
        #pragma unroll
        for (int off = 1; off < 64; off <<= 1) {
            int t = __shfl_up(x, off, 64);
            if (lane >= off) x += t;
        }
        if (lane == 63) wsum[wid] = x;
        __syncthreads();
        if (wid == 0 && lane < 16) {
            int s = wsum[lane];
            #pragma unroll
            for (int off = 1; off < 16; off <<= 1) {
                int t = __shfl_up(s, off, 16);
                if ((lane & 15) >= off) s += t;
            }
            wsum[lane] = s;
        }
        __syncthreads();
        int woff = (wid == 0) ? 0 : wsum[wid - 1];
        int incl = x + woff;
        if (i < n) row_ptr[i] = carry_s + incl - v;
        __syncthreads();
        if (tid == 0) carry_s += wsum[15];
        __syncthreads();
    }
    if (tid == 0) row_ptr[n] = carry_s;
}

__global__ void k_fill(const int* __restrict__ ei, const int* __restrict__ row_ptr,
                       int* __restrict__ fill, const float* __restrict__ dinv,
                       int* __restrict__ eidx, float* __restrict__ wsp, int E) {
    int e = blockIdx.x * blockDim.x + threadIdx.x;
    if (e < E) {
        int src = ei[e];
        int dst = ei[E + e];
        int pos = atomicAdd(&fill[dst], 1);
        eidx[row_ptr[dst] + pos] = src;
        atomicAdd(&wsp[dst], dinv[src] * dinv[dst]);
    }
}

__global__ void k_wspfin(float* __restrict__ wsp, const float* __restrict__ self_norm, int N) {
    int n = blockIdx.x * blockDim.x + threadIdx.x;
    if (n < N) wsp[n] += self_norm[n];
}

__global__ void k_init_affine(float* __restrict__ s, float* __restrict__ sh,
                              float* __restrict__ sums) {
    int c = threadIdx.x;
    s[c] = 1.0f;
    sh[c] = 0.0f;
    sums[c] = 0.f;
    sums[256 + c] = 0.f;
}

// ---------------- W prep: Wt[n][k] = (scale?scale[k]:1) * W[k][n], bf16 ----------------
__global__ void k_prepW(const float* __restrict__ W, const float* __restrict__ scale,
                        unsigned short* __restrict__ Wt, int K, int DO) {
    int idx = blockIdx.x * blockDim.x + threadIdx.x;
    if (idx < K * DO) {
        int k = idx / DO, n = idx % DO;
        float v = W[idx];
        if (scale) v *= scale[k];
        Wt[(size_t)n * K + k] = f2bf(v);
    }
}

// d[c] = sum_k sh[k] * W[k][c]
__global__ void k_prepd(const float* __restrict__ W, const float* __restrict__ sh,
                        float* __restrict__ d, int K, int DO) {
    int c = blockIdx.x * blockDim.x + threadIdx.x;
    if (c < DO) {
        float a = 0.f;
        for (int k = 0; k < K; ++k) a += sh[k] * W[(size_t)k * DO + c];
        d[c] = a;
    }
}

// ---------------- wave-per-node aggregation, unroll-4, contiguous group split ----
// conv[n] = dn*( sum_e dinv[src]*h[src] + dn*h[n] ),  dn = dinv[n]
// non-EPI: o = s[c]*conv + sh[c]*wsp[n]
// EPI:     o = leaky(conv + wsp[n]*dv[c] + bias[c])
template<int COLS, bool EPI>
__global__ __launch_bounds__(256) void k_aggw(const unsigned short* __restrict__ h,
    const float* __restrict__ s, const float* __restrict__ sh,
    const float* __restrict__ dv, const float* __restrict__ bias,
    const int* __restrict__ row_ptr, const int* __restrict__ eidx,
    const float* __restrict__ dinv, const float* __restrict__ wsp,
    unsigned short* __restrict__ t, int N) {
    constexpr int LPR = COLS / 8;          // lanes per row: 16 or 32
    constexpr int GR  = 64 / LPR;          // groups per wave: 4 or 2
    constexpr int SH  = (COLS == 256) ? 8 : 7;   // log2(COLS) (element shift)
    int n = blockIdx.x * 4 + (threadIdx.x >> 6);
    if (n >= N) return;
    int l = threadIdx.x & 63;
    int ct = l & (LPR - 1);
    int gp = l / LPR;
    const unsigned short* up = h + ct * 8;
    int b = row_ptr[n], e = row_ptr[n + 1];
    int cnt = e - b;
    int per = (cnt + GR - 1) / GR;
    int jb = b + gp * per;
    int je = min(jb + per, e);
    float dn = dinv[n];
    float acc[8] = {};
    if (gp == 0) {            // self term, weight dn
        short8 hv = *(const short8*)(up + ((size_t)n << SH));
        #pragma unroll
        for (int i = 0; i < 8; ++i) acc[i] += dn * bf2f((unsigned short)hv[i]);
    }
    int j = jb;
    for (; j + 4 <= je; j += 4) {
        int s0 = eidx[j], s1 = eidx[j + 1], s2 = eidx[j + 2], s3 = eidx[j + 3];
        float d0 = dinv[s0], d1 = dinv[s1], d2 = dinv[s2], d3 = dinv[s3];
        short8 r0 = *(const short8*)(up + ((size_t)s0 << SH));
        short8 r1 = *(const short8*)(up + ((size_t)s1 << SH));
        short8 r2 = *(const short8*)(up + ((size_t)s2 << SH));
        short8 r3 = *(const short8*)(up + ((size_t)s3 << SH));
        #pragma unroll
        for (int i = 0; i < 8; ++i) {
            float a01 = d0 * bf2f((unsigned short)r0[i]) + d1 * bf2f((unsigned short)r1[i]);
            float a23 = d2 * bf2f((unsigned short)r2[i]) + d3 * bf2f((unsigned short)r3[i]);
            acc[i] += a01 + a23;
        }
    }
    for (; j < je; ++j) {
        int s0 = eidx[j];
        float d0 = dinv[s0];
        short8 r0 = *(const short8*)(up + ((size_t)s0 << SH));
        #pragma unroll
        for (int i = 0; i < 8; ++i) acc[i] += d0 * bf2f((unsigned short)r0[i]);
    }
    #pragma unroll
    for (int mask = LPR; mask < 64; mask <<= 1) {
        #pragma unroll
        for (int i = 0; i < 8; ++i) acc[i] += __shfl_xor(acc[i], mask, 64);
    }
    if (gp == 0) {
        float wn = wsp[n];
        short8 ov;
        #pragma unroll
        for (int i = 0; i < 8; ++i) {
            int col = ct * 8 + i;
            float o;
            if constexpr (EPI) {
                o = dn * acc[i] + wn * dv[col] + bias[col];
                o = o > 0.f ? o : NEG_SLOPE * o;
            } else {
                o = s[col] * (dn * acc[i]) + sh[col] * wn;
            }
            ov[i] = (short)f2bf(o);
        }
        *(short8*)(t + ((size_t)n << SH) + ct * 8) = ov;
    }
}

// ---------------- staged MFMA GEMM ----------------
// A: [M x K] bf16, Wt: [DO x K] bf16. Tile 128x128, BK=64, 4 waves.
// LDS tiles [128 rows][8 slots of 16B], slot XOR-swizzled by (row&7).
// global_load_lds writes linearly -> inverse-swizzle the global SOURCE (rule 21).
template<int K, int DO, bool FUSE>
__global__ __launch_bounds__(256) void k_mfma2(
    const unsigned short* __restrict__ A, const unsigned short* __restrict__ Wt,
    const float* __restrict__ bias, unsigned short* __restrict__ H,
    float* __restrict__ sums, int M) {
    __shared__ unsigned short Asm[128 * 64];
    __shared__ unsigned short Bsm[128 * 64];
    __shared__ float ls[2][128];
    int tid = threadIdx.x;
    int l = tid & 63, w = tid >> 6;
    int wr = w & 1, wc = w >> 1;
    int rl = l & 15, kh = l >> 4;
    int Rb = blockIdx.x * 128;
    int Cb = blockIdx.y * 128;
    int srow = tid >> 3;
    int sd   = tid & 7;
    f32x4 acc[4][4] = {};
    for (int k0 = 0; k0 < K; k0 += 64) {
        #pragma unroll
        for (int i = 0; i < 4; ++i) {
            int row = i * 32 + srow;
            int ss = sd ^ (row & 7);
            int rg = Rb + row; if (rg >= M) rg = M - 1;
            gload_lds16(A + (size_t)rg * K + k0 + ss * 8,
                        (char*)Asm + i * 4096 + w * 1024);
            gload_lds16(Wt + (size_t)(Cb + row) * K + k0 + ss * 8,
                        (char*)Bsm + i * 4096 + w * 1024);
        }
        __syncthreads();
        #pragma unroll
        for (int kk = 0; kk < 2; ++kk) {
            short8 af[4], bf[4];
            #pragma unroll
            for (int mf = 0; mf < 4; ++mf) {
                int r = wr * 64 + mf * 16 + rl;
                int slot = (kk * 4 + kh) ^ (r & 7);
                af[mf] = *(const short8*)((const char*)Asm + r * 128 + slot * 16);
            }
            #pragma unroll
            for (int nf = 0; nf < 4; ++nf) {
                int c = wc * 64 + nf * 16 + rl;
                int slot = (kk * 4 + kh) ^ (c & 7);
                bf[nf] = *(const short8*)((const char*)Bsm + c * 128 + slot * 16);
            }
            #pragma unroll
            for (int mf = 0; mf < 4; ++mf)
                #pragma unroll
                for (int nf = 0; nf < 4; ++nf)
                    acc[mf][nf] = __builtin_amdgcn_mfma_f32_16x16x32_bf16(
                        af[mf], bf[nf], acc[mf][nf], 0, 0, 0);
        }
        __syncthreads();
    }
    if constexpr (FUSE) {
        for (int c = tid; c < 128; c += 256) { ls[0][c] = 0.f; ls[1][c] = 0.f; }
        __syncthreads();
    }
    #pragma unroll
    for (int nf = 0; nf < 4; ++nf) {
        int cl = wc * 64 + nf * 16 + rl;
        int col = Cb + cl;
        float bcol = FUSE ? bias[col] : 0.f;
        float p1 = 0.f, p2 = 0.f;
        #pragma unroll
        for (int mf = 0; mf < 4; ++mf) {
            #pragma unroll
            for (int r = 0; r < 4; ++r) {
                int row = Rb + wr * 64 + mf * 16 + kh * 4 + r;
                if (row < M) {
                    if constexpr (FUSE) {
                        float z = acc[mf][nf][r] + bcol;
                        z = z > 0.f ? z : NEG_SLOPE * z;
                        H[(size_t)row * DO + col] = f2bf(z);
                        p1 += z; p2 += z * z;
                    } else {
                        H[(size_t)row * DO + col] = f2bf(acc[mf][nf][r]);
                    }
                }
            }
        }
        if constexpr (FUSE) {
            atomicAdd(&ls[0][cl], p1);
            atomicAdd(&ls[1][cl], p2);
        }
    }
    if constexpr (FUSE) {
        __syncthreads();
        for (int c = tid; c < 128; c += 256) {
            atomicAdd(&sums[Cb + c], ls[0][c]);
            atomicAdd(&sums[256 + Cb + c], ls[1][c]);
        }
    }
}

// ---------------- BN stats over bf16 [M x 128] ----------------
__global__ void k_stats_bf(const unsigned short* __restrict__ h, float* __restrict__ sums, int M) {
    int c = threadIdx.x;
    float s1 = 0.f, s2 = 0.f;
    for (int r = blockIdx.x; r < M; r += gridDim.x) {
        float v = bf2f(h[(size_t)r * 128 + c]);
        s1 += v; s2 += v * v;
    }
    atomicAdd(&sums[c], s1);
    atomicAdd(&sums[256 + c], s2);
}

// ---------------- BN finalize -> affine (also re-zeroes sums for next layer) ----
__global__ void k_finalize(float* __restrict__ sums, const float* __restrict__ g,
                           const float* __restrict__ bt, float* __restrict__ s_out,
                           float* __restrict__ sh_out, float Nf) {
    int c = threadIdx.x;
    float mu = sums[c] / Nf;
    float var = sums[256 + c] / Nf - mu * mu;
    float rs = rsqrtf(var + BN_EPS);
    float sc = g[c] * rs;
    s_out[c] = sc;
    sh_out[c] = bt[c] - mu * sc;
    sums[c] = 0.f;
    sums[256 + c] = 0.f;
}

// ---------------- global mean pool, two-stage ----------------
__global__ void k_pool1(const unsigned short* __restrict__ h, const int* __restrict__ batch,
                        float* __restrict__ part, int N) {
    int g = blockIdx.x;
    int sidx = blockIdx.y;
    int c = threadIdx.x;
    int lo = 0, hi = N;
    while (lo < hi) { int m = (lo + hi) >> 1; if (batch[m] < g) lo = m + 1; else hi = m; }
    int start = lo; hi = N;
    while (lo < hi) { int m = (lo + hi) >> 1; if (batch[m] < g + 1) lo = m + 1; else hi = m; }
    int end = lo;
    float acc = 0.f;
    for (int r = start + sidx; r < end; r += POOL_S)
        acc += bf2f(h[(size_t)r * 128 + c]);
    part[((size_t)g * POOL_S + sidx) * 128 + c] = acc;
}

__global__ void k_pool2(const float* __restrict__ part, const int* __restrict__ batch,
                        const float* __restrict__ s, const float* __restrict__ sh,
                        float* __restrict__ out, int N) {
    int g = blockIdx.x;
    int c = threadIdx.x;
    int lo = 0, hi = N;
    while (lo < hi) { int m = (lo + hi) >> 1; if (batch[m] < g) lo = m + 1; else hi = m; }
    int start = lo; hi = N;
    while (lo < hi) { int m = (lo + hi) >> 1; if (batch[m] < g + 1) lo = m + 1; else hi = m; }
    int cnt = lo - start;
    float acc = 0.f;
    #pragma unroll
    for (int i = 0; i < POOL_S; ++i) acc += part[((size_t)g * POOL_S + i) * 128 + c];
    out[(size_t)g * 128 + c] = (cnt > 0) ? (s[c] * acc / (float)cnt + sh[c]) : 0.f;
}

// ---------------- host ----------------

static inline size_t align256(size_t x) { return (x + 255) & ~(size_t)255; }

extern "C" void kernel_launch(void* const* d_in, const int* in_sizes, int n_in,
                              void* d_out, int out_size, void* d_ws, size_t ws_size,
                              hipStream_t stream) {
    const float* x   = (const float*)d_in[0];
    const int* ei    = (const int*)d_in[1];
    const int* batch = (const int*)d_in[2];
    const float* Wp[4]  = {(const float*)d_in[3], (const float*)d_in[7],
                           (const float*)d_in[11], (const float*)d_in[15]};
    const float* bp[4]  = {(const float*)d_in[4], (const float*)d_in[8],
                           (const float*)d_in[12], (const float*)d_in[16]};
    const float* gp[4]  = {(const float*)d_in[5], (const float*)d_in[9],
                           (const float*)d_in[13], (const float*)d_in[17]};
    const float* btp[4] = {(const float*)d_in[6], (const float*)d_in[10],
                           (const float*)d_in[14], (const float*)d_in[18]};

    const int N = in_sizes[0] / 128;
    const int E = in_sizes[1] / 2;
    const int G = out_size / 128;

    char* p = (char*)d_ws;
    int* deg_cnt = (int*)p;            p += align256((size_t)N * 4);
    int* row_ptr = (int*)p;            p += align256((size_t)(N + 1) * 4);
    float* dinv = (float*)p;           p += align256((size_t)N * 4);
    float* self_norm = (float*)p;      p += align256((size_t)N * 4);
    float* wsp = (float*)p;            p += align256((size_t)N * 4);
    int* eidx = (int*)p;               p += align256((size_t)E * 4);
    float* sums = (float*)p;           p += align256(512 * 4);
    float* s_arr = (float*)p;          p += align256(5 * 256 * 4);
    float* sh_arr = (float*)p;         p += align256(5 * 256 * 4);
    float* dvec = (float*)p;           p += align256(256 * 4);
    unsigned short* Wt = (unsigned short*)p; p += align256(256 * 256 * 2);
    float* part = (float*)p;           p += align256((size_t)G * POOL_S * 128 * 4);
    unsigned short* xb = (unsigned short*)p;   p += align256((size_t)N * 128 * 2);
    unsigned short* bufA = (unsigned short*)p; p += align256((size_t)N * 256 * 2);
    unsigned short* bufB = (unsigned short*)p; p += align256((size_t)N * 256 * 2);

    k_cvt<<<(N * 128 / 8 + 255) / 256, 256, 0, stream>>>(x, xb, N * 128 / 8);

    hipMemsetAsync(deg_cnt, 0, (size_t)N * 4, stream);
    hipMemsetAsync(wsp, 0, (size_t)N * 4, stream);
    k_count<<<(E + 255) / 256, 256, 0, stream>>>(ei, deg_cnt, E);
    k_deg<<<(N + 255) / 256, 256, 0, stream>>>(deg_cnt, dinv, self_norm, N);
    k_scan<<<1, 1024, 0, stream>>>(deg_cnt, row_ptr, N);
    hipMemsetAsync(deg_cnt, 0, (size_t)N * 4, stream);
    k_fill<<<(E + 255) / 256, 256, 0, stream>>>(ei, row_ptr, deg_cnt, dinv, eidx, wsp, E);
    k_wspfin<<<(N + 255) / 256, 256, 0, stream>>>(wsp, self_norm, N);
    k_init_affine<<<1, 256, 0, stream>>>(s_arr, sh_arr, sums);

    const int ablocks = (N + 3) / 4;
    const int gx = (N + 127) / 128;

    // ---- L1: agg(xb) [N,128] -> mfma 128->256 fused ----
    k_aggw<128, false><<<ablocks, 256, 0, stream>>>(xb, s_arr, sh_arr, nullptr, nullptr,
        row_ptr, eidx, dinv, wsp, bufA, N);
    k_prepW<<<(128 * 256 + 255) / 256, 256, 0, stream>>>(Wp[0], nullptr, Wt, 128, 256);
    k_mfma2<128, 256, true><<<dim3(gx, 2), 256, 0, stream>>>(bufA, Wt, bp[0], bufB, sums, N);
    k_finalize<<<1, 256, 0, stream>>>(sums, gp[0], btp[0], s_arr + 256, sh_arr + 256, (float)N);

    // ---- L2, L3 ----
    for (int L = 1; L <= 2; ++L) {
        k_aggw<256, false><<<ablocks, 256, 0, stream>>>(bufB, s_arr + L * 256, sh_arr + L * 256,
            nullptr, nullptr, row_ptr, eidx, dinv, wsp, bufA, N);
        k_prepW<<<(256 * 256 + 255) / 256, 256, 0, stream>>>(Wp[L], nullptr, Wt, 256, 256);
        k_mfma2<256, 256, true><<<dim3(gx, 2), 256, 0, stream>>>(bufA, Wt, bp[L], bufB, sums, N);
        k_finalize<<<1, 256, 0, stream>>>(sums, gp[L], btp[L],
                                          s_arr + (L + 1) * 256, sh_arr + (L + 1) * 256, (float)N);
    }

    // ---- L4: GEMM-first (fold s3 into W, sh3 into dvec), then agg in 128 cols ----
    k_prepW<<<(256 * 128 + 255) / 256, 256, 0, stream>>>(Wp[3], s_arr + 3 * 256, Wt, 256, 128);
    k_prepd<<<1, 128, 0, stream>>>(Wp[3], sh_arr + 3 * 256, dvec, 256, 128);
    k_mfma2<256, 128, false><<<dim3(gx, 1), 256, 0, stream>>>(bufB, Wt, nullptr, bufA, nullptr, N);
    k_aggw<128, true><<<ablocks, 256, 0, stream>>>(bufA, nullptr, nullptr, dvec, bp[3],
        row_ptr, eidx, dinv, wsp, bufB, N);
    k_stats_bf<<<256, 128, 0, stream>>>(bufB, sums, N);
    k_finalize<<<1, 128, 0, stream>>>(sums, gp[3], btp[3], s_arr + 4 * 256, sh_arr + 4 * 256, (float)N);

    dim3 pgrid(G, POOL_S);
    k_pool1<<<pgrid, 128, 0, stream>>>(bufB, batch, part, N);
    k_pool2<<<G, 128, 0, stream>>>(part, batch, s_arr + 4 * 256, sh_arr + 4 * 256,
                                   (float*)d_out, N);
}

// Round 7
// 566.267 us; speedup vs baseline: 1.1380x; 1.1380x over previous
//
#include <hip/hip_runtime.h>
#include <hip/hip_bf16.h>

#define NEG_SLOPE 0.01f
#define BN_EPS 1e-5f
#define POOL_S 16

typedef __attribute__((ext_vector_type(8))) short short8;
typedef __attribute__((ext_vector_type(4))) float f32x4;

__device__ __forceinline__ float bf2f(unsigned short b) {
    unsigned int u = ((unsigned int)b) << 16;
    float f; __builtin_memcpy(&f, &u, 4); return f;
}
__device__ __forceinline__ unsigned short f2bf(float f) {
    unsigned int u; __builtin_memcpy(&u, &f, 4);
    u = (u + 0x7FFFu + ((u >> 16) & 1u)) >> 16;
    return (unsigned short)u;
}

__device__ __forceinline__ void gload_lds16(const void* g, void* l) {
    __builtin_amdgcn_global_load_lds(
        (const __attribute__((address_space(1))) void*)g,
        (__attribute__((address_space(3))) void*)l, 16, 0, 0);
}

// ---------------- x fp32 -> bf16 ----------------
__global__ void k_cvt(const float* __restrict__ x, unsigned short* __restrict__ xb, int total8) {
    int i = blockIdx.x * blockDim.x + threadIdx.x;
    if (i < total8) {
        float4 a = ((const float4*)x)[i * 2];
        float4 b = ((const float4*)x)[i * 2 + 1];
        short8 o;
        o[0] = (short)f2bf(a.x); o[1] = (short)f2bf(a.y);
        o[2] = (short)f2bf(a.z); o[3] = (short)f2bf(a.w);
        o[4] = (short)f2bf(b.x); o[5] = (short)f2bf(b.y);
        o[6] = (short)f2bf(b.z); o[7] = (short)f2bf(b.w);
        ((short8*)xb)[i] = o;
    }
}

// ---------------- CSR build ----------------
__global__ void k_count(const int* __restrict__ ei, int* __restrict__ cnt, int E) {
    int e = blockIdx.x * blockDim.x + threadIdx.x;
    if (e < E) atomicAdd(&cnt[ei[E + e]], 1);
}

__global__ void k_deg(const int* __restrict__ cnt, float* __restrict__ dinv, int N) {
    int n = blockIdx.x * blockDim.x + threadIdx.x;
    if (n < N) dinv[n] = rsqrtf((float)(cnt[n] + 1));
}

// ---- hierarchical exclusive scan: cnt[0..n) -> row_ptr[0..n], row_ptr[n]=total ----
// k_scan1: per-1024-elem block sums. k_scan2: 1-wave scan of partials (<=64).
// k_scan3: local scan + block offset.
__global__ __launch_bounds__(256) void k_scan1(const int* __restrict__ cnt,
                                               int* __restrict__ bsum, int n) {
    int b = blockIdx.x;
    int t = threadIdx.x;
    int base = b * 1024 + t * 4;
    int s = 0;
    #pragma unroll
    for (int i = 0; i < 4; ++i) s += (base + i < n) ? cnt[base + i] : 0;
    // wave reduce
    #pragma unroll
    for (int off = 1; off < 64; off <<= 1) s += __shfl_xor(s, off, 64);
    __shared__ int ws[4];
    if ((t & 63) == 0) ws[t >> 6] = s;
    __syncthreads();
    if (t == 0) bsum[b] = ws[0] + ws[1] + ws[2] + ws[3];
}

__global__ void k_scan2(const int* __restrict__ bsum, int* __restrict__ boff,
                        int* __restrict__ row_ptr, int nb, int n) {
    int lane = threadIdx.x;    // 64
    int v = (lane < nb) ? bsum[lane] : 0;
    int x = v;
    #pragma unroll
    for (int off = 1; off < 64; off <<= 1) {
        int t = __shfl_up(x, off, 64);
        if (lane >= off) x += t;
    }
    if (lane < nb) boff[lane] = x - v;
    if (lane == 63) row_ptr[n] = x;
}

__global__ __launch_bounds__(256) void k_scan3(const int* __restrict__ cnt,
                                               const int* __restrict__ boff,
                                               int* __restrict__ row_ptr, int n) {
    int b = blockIdx.x;
    int t = threadIdx.x;
    int lane = t & 63, w = t >> 6;
    int base = b * 1024 + t * 4;
    int v[4];
    #pragma unroll
    for (int i = 0; i < 4; ++i) v[i] = (base + i < n) ? cnt[base + i] : 0;
    int tsum = v[0] + v[1] + v[2] + v[3];
    int x = tsum;
    #pragma unroll
    for (int off = 1; off < 64; off <<= 1) {
        int tt = __shfl_up(x, off, 64);
        if (lane >= off) x += tt;
    }
    __shared__ int ws[4];
    if (lane == 63) ws[w] = x;
    __syncthreads();
    int woff = 0;
    for (int k = 0; k < 4; ++k) if (k < w) woff += ws[k];
    int excl = boff[b] + woff + x - tsum;
    #pragma unroll
    for (int i = 0; i < 4; ++i) {
        if (base + i < n) row_ptr[base + i] = excl;
        excl += v[i];
    }
}

__global__ void k_fill(const int* __restrict__ ei, const int* __restrict__ row_ptr,
                       int* __restrict__ fill, int* __restrict__ eidx, int E) {
    int e = blockIdx.x * blockDim.x + threadIdx.x;
    if (e < E) {
        int src = ei[e];
        int dst = ei[E + e];
        int pos = atomicAdd(&fill[dst], 1);
        eidx[row_ptr[dst] + pos] = src;
    }
}

__global__ void k_init_affine(float* __restrict__ s, float* __restrict__ sh,
                              float* __restrict__ sums) {
    int c = threadIdx.x;
    s[c] = 1.0f;
    sh[c] = 0.0f;
    sums[c] = 0.f;
    sums[256 + c] = 0.f;
}

// ---------------- W prep: Wt[n][k] = (scale?scale[k]:1) * W[k][n], bf16 ----------------
__global__ void k_prepW(const float* __restrict__ W, const float* __restrict__ scale,
                        unsigned short* __restrict__ Wt, int K, int DO) {
    int idx = blockIdx.x * blockDim.x + threadIdx.x;
    if (idx < K * DO) {
        int k = idx / DO, n = idx % DO;
        float v = W[idx];
        if (scale) v *= scale[k];
        Wt[(size_t)n * K + k] = f2bf(v);
    }
}

// d[c] = sum_k sh[k] * W[k][c]
__global__ void k_prepd(const float* __restrict__ W, const float* __restrict__ sh,
                        float* __restrict__ d, int K, int DO) {
    int c = blockIdx.x * blockDim.x + threadIdx.x;
    if (c < DO) {
        float a = 0.f;
        for (int k = 0; k < K; ++k) a += sh[k] * W[(size_t)k * DO + c];
        d[c] = a;
    }
}

// ---------------- wave-per-node aggregation, unroll-4, in-register wsum ----
// conv[n] = dn*( sum_e dinv[src]*h[src] + dn*h[n] ),  dn = dinv[n]
// ws      = dn*sum_e dinv[src] + dn*dn
// non-EPI: o = s[c]*conv + sh[c]*ws
// EPI:     o = leaky(conv + ws*dv[c] + bias[c])
template<int COLS, bool EPI>
__global__ __launch_bounds__(256) void k_aggw(const unsigned short* __restrict__ h,
    const float* __restrict__ s, const float* __restrict__ sh,
    const float* __restrict__ dv, const float* __restrict__ bias,
    const int* __restrict__ row_ptr, const int* __restrict__ eidx,
    const float* __restrict__ dinv, unsigned short* __restrict__ t, int N) {
    constexpr int LPR = COLS / 8;          // lanes per row: 16 or 32
    constexpr int GR  = 64 / LPR;          // groups per wave: 4 or 2
    constexpr int SH  = (COLS == 256) ? 8 : 7;
    int n = blockIdx.x * 4 + (threadIdx.x >> 6);
    if (n >= N) return;
    int l = threadIdx.x & 63;
    int ct = l & (LPR - 1);
    int gp = l / LPR;
    const unsigned short* up = h + ct * 8;
    int b = row_ptr[n], e = row_ptr[n + 1];
    int cnt = e - b;
    int per = (cnt + GR - 1) / GR;
    int jb = b + gp * per;
    int je = min(jb + per, e);
    float dn = dinv[n];
    float acc[8] = {};
    float ssum = 0.f;
    if (gp == 0) {            // self term, weight dn (overall dn^2 after conv scale)
        short8 hv = *(const short8*)(up + ((size_t)n << SH));
        #pragma unroll
        for (int i = 0; i < 8; ++i) acc[i] += dn * bf2f((unsigned short)hv[i]);
    }
    int j = jb;
    for (; j + 4 <= je; j += 4) {
        int s0 = eidx[j], s1 = eidx[j + 1], s2 = eidx[j + 2], s3 = eidx[j + 3];
        float d0 = dinv[s0], d1 = dinv[s1], d2 = dinv[s2], d3 = dinv[s3];
        short8 r0 = *(const short8*)(up + ((size_t)s0 << SH));
        short8 r1 = *(const short8*)(up + ((size_t)s1 << SH));
        short8 r2 = *(const short8*)(up + ((size_t)s2 << SH));
        short8 r3 = *(const short8*)(up + ((size_t)s3 << SH));
        ssum += (d0 + d1) + (d2 + d3);
        #pragma unroll
        for (int i = 0; i < 8; ++i) {
            float a01 = d0 * bf2f((unsigned short)r0[i]) + d1 * bf2f((unsigned short)r1[i]);
            float a23 = d2 * bf2f((unsigned short)r2[i]) + d3 * bf2f((unsigned short)r3[i]);
            acc[i] += a01 + a23;
        }
    }
    for (; j < je; ++j) {
        int s0 = eidx[j];
        float d0 = dinv[s0];
        ssum += d0;
        short8 r0 = *(const short8*)(up + ((size_t)s0 << SH));
        #pragma unroll
        for (int i = 0; i < 8; ++i) acc[i] += d0 * bf2f((unsigned short)r0[i]);
    }
    #pragma unroll
    for (int mask = LPR; mask < 64; mask <<= 1) {
        #pragma unroll
        for (int i = 0; i < 8; ++i) acc[i] += __shfl_xor(acc[i], mask, 64);
        ssum += __shfl_xor(ssum, mask, 64);
    }
    if (gp == 0) {
        float ws = dn * ssum + dn * dn;
        short8 ov;
        #pragma unroll
        for (int i = 0; i < 8; ++i) {
            int col = ct * 8 + i;
            float o;
            if constexpr (EPI) {
                o = dn * acc[i] + ws * dv[col] + bias[col];
                o = o > 0.f ? o : NEG_SLOPE * o;
            } else {
                o = s[col] * (dn * acc[i]) + sh[col] * ws;
            }
            ov[i] = (short)f2bf(o);
        }
        *(short8*)(t + ((size_t)n << SH) + ct * 8) = ov;
    }
}

// ---------------- staged MFMA GEMM ----------------
// A: [M x K] bf16, Wt: [DO x K] bf16. Tile 128x128, BK=64, 4 waves.
// LDS tiles [128 rows][8 slots of 16B], slot XOR-swizzled by (row&7).
// global_load_lds writes linearly -> inverse-swizzle the global SOURCE (rule 21).
template<int K, int DO, bool FUSE>
__global__ __launch_bounds__(256) void k_mfma2(
    const unsigned short* __restrict__ A, const unsigned short* __restrict__ Wt,
    const float* __restrict__ bias, unsigned short* __restrict__ H,
    float* __restrict__ sums, int M) {
    __shared__ unsigned short Asm[128 * 64];
    __shared__ unsigned short Bsm[128 * 64];
    __shared__ float ls[2][128];
    int tid = threadIdx.x;
    int l = tid & 63, w = tid >> 6;
    int wr = w & 1, wc = w >> 1;
    int rl = l & 15, kh = l >> 4;
    int Rb = blockIdx.x * 128;
    int Cb = blockIdx.y * 128;
    int srow = tid >> 3;
    int sd   = tid & 7;
    f32x4 acc[4][4] = {};
    for (int k0 = 0; k0 < K; k0 += 64) {
        #pragma unroll
        for (int i = 0; i < 4; ++i) {
            int row = i * 32 + srow;
            int ss = sd ^ (row & 7);
            int rg = Rb + row; if (rg >= M) rg = M - 1;
            gload_lds16(A + (size_t)rg * K + k0 + ss * 8,
                        (char*)Asm + i * 4096 + w * 1024);
            gload_lds16(Wt + (size_t)(Cb + row) * K + k0 + ss * 8,
                        (char*)Bsm + i * 4096 + w * 1024);
        }
        __syncthreads();
        #pragma unroll
        for (int kk = 0; kk < 2; ++kk) {
            short8 af[4], bf[4];
            #pragma unroll
            for (int mf = 0; mf < 4; ++mf) {
                int r = wr * 64 + mf * 16 + rl;
                int slot = (kk * 4 + kh) ^ (r & 7);
                af[mf] = *(const short8*)((const char*)Asm + r * 128 + slot * 16);
            }
            #pragma unroll
            for (int nf = 0; nf < 4; ++nf) {
                int c = wc * 64 + nf * 16 + rl;
                int slot = (kk * 4 + kh) ^ (c & 7);
                bf[nf] = *(const short8*)((const char*)Bsm + c * 128 + slot * 16);
            }
            #pragma unroll
            for (int mf = 0; mf < 4; ++mf)
                #pragma unroll
                for (int nf = 0; nf < 4; ++nf)
                    acc[mf][nf] = __builtin_amdgcn_mfma_f32_16x16x32_bf16(
                        af[mf], bf[nf], acc[mf][nf], 0, 0, 0);
        }
        __syncthreads();
    }
    if constexpr (FUSE) {
        for (int c = tid; c < 128; c += 256) { ls[0][c] = 0.f; ls[1][c] = 0.f; }
        __syncthreads();
    }
    #pragma unroll
    for (int nf = 0; nf < 4; ++nf) {
        int cl = wc * 64 + nf * 16 + rl;
        int col = Cb + cl;
        float bcol = FUSE ? bias[col] : 0.f;
        float p1 = 0.f, p2 = 0.f;
        #pragma unroll
        for (int mf = 0; mf < 4; ++mf) {
            #pragma unroll
            for (int r = 0; r < 4; ++r) {
                int row = Rb + wr * 64 + mf * 16 + kh * 4 + r;
                if (row < M) {
                    if constexpr (FUSE) {
                        float z = acc[mf][nf][r] + bcol;
                        z = z > 0.f ? z : NEG_SLOPE * z;
                        H[(size_t)row * DO + col] = f2bf(z);
                        p1 += z; p2 += z * z;
                    } else {
                        H[(size_t)row * DO + col] = f2bf(acc[mf][nf][r]);
                    }
                }
            }
        }
        if constexpr (FUSE) {
            atomicAdd(&ls[0][cl], p1);
            atomicAdd(&ls[1][cl], p2);
        }
    }
    if constexpr (FUSE) {
        __syncthreads();
        for (int c = tid; c < 128; c += 256) {
            atomicAdd(&sums[Cb + c], ls[0][c]);
            atomicAdd(&sums[256 + Cb + c], ls[1][c]);
        }
    }
}

// ---------------- BN stats over bf16 [M x 128] ----------------
__global__ void k_stats_bf(const unsigned short* __restrict__ h, float* __restrict__ sums, int M) {
    int c = threadIdx.x;
    float s1 = 0.f, s2 = 0.f;
    for (int r = blockIdx.x; r < M; r += gridDim.x) {
        float v = bf2f(h[(size_t)r * 128 + c]);
        s1 += v; s2 += v * v;
    }
    atomicAdd(&sums[c], s1);
    atomicAdd(&sums[256 + c], s2);
}

// ---------------- BN finalize -> affine (re-zeroes sums) ----------------
__global__ void k_finalize(float* __restrict__ sums, const float* __restrict__ g,
                           const float* __restrict__ bt, float* __restrict__ s_out,
                           float* __restrict__ sh_out, float Nf) {
    int c = threadIdx.x;
    float mu = sums[c] / Nf;
    float var = sums[256 + c] / Nf - mu * mu;
    float rs = rsqrtf(var + BN_EPS);
    float sc = g[c] * rs;
    s_out[c] = sc;
    sh_out[c] = bt[c] - mu * sc;
    sums[c] = 0.f;
    sums[256 + c] = 0.f;
}

// ---------------- global mean pool, two-stage ----------------
__global__ void k_pool1(const unsigned short* __restrict__ h, const int* __restrict__ batch,
                        float* __restrict__ part, int N) {
    int g = blockIdx.x;
    int sidx = blockIdx.y;
    int c = threadIdx.x;
    int lo = 0, hi = N;
    while (lo < hi) { int m = (lo + hi) >> 1; if (batch[m] < g) lo = m + 1; else hi = m; }
    int start = lo; hi = N;
    while (lo < hi) { int m = (lo + hi) >> 1; if (batch[m] < g + 1) lo = m + 1; else hi = m; }
    int end = lo;
    float acc = 0.f;
    for (int r = start + sidx; r < end; r += POOL_S)
        acc += bf2f(h[(size_t)r * 128 + c]);
    part[((size_t)g * POOL_S + sidx) * 128 + c] = acc;
}

__global__ void k_pool2(const float* __restrict__ part, const int* __restrict__ batch,
                        const float* __restrict__ s, const float* __restrict__ sh,
                        float* __restrict__ out, int N) {
    int g = blockIdx.x;
    int c = threadIdx.x;
    int lo = 0, hi = N;
    while (lo < hi) { int m = (lo + hi) >> 1; if (batch[m] < g) lo = m + 1; else hi = m; }
    int start = lo; hi = N;
    while (lo < hi) { int m = (lo + hi) >> 1; if (batch[m] < g + 1) lo = m + 1; else hi = m; }
    int cnt = lo - start;
    float acc = 0.f;
    #pragma unroll
    for (int i = 0; i < POOL_S; ++i) acc += part[((size_t)g * POOL_S + i) * 128 + c];
    out[(size_t)g * 128 + c] = (cnt > 0) ? (s[c] * acc / (float)cnt + sh[c]) : 0.f;
}

// ---------------- host ----------------

static inline size_t align256(size_t x) { return (x + 255) & ~(size_t)255; }

extern "C" void kernel_launch(void* const* d_in, const int* in_sizes, int n_in,
                              void* d_out, int out_size, void* d_ws, size_t ws_size,
                              hipStream_t stream) {
    const float* x   = (const float*)d_in[0];
    const int* ei    = (const int*)d_in[1];
    const int* batch = (const int*)d_in[2];
    const float* Wp[4]  = {(const float*)d_in[3], (const float*)d_in[7],
                           (const float*)d_in[11], (const float*)d_in[15]};
    const float* bp[4]  = {(const float*)d_in[4], (const float*)d_in[8],
                           (const float*)d_in[12], (const float*)d_in[16]};
    const float* gp[4]  = {(const float*)d_in[5], (const float*)d_in[9],
                           (const float*)d_in[13], (const float*)d_in[17]};
    const float* btp[4] = {(const float*)d_in[6], (const float*)d_in[10],
                           (const float*)d_in[14], (const float*)d_in[18]};

    const int N = in_sizes[0] / 128;
    const int E = in_sizes[1] / 2;
    const int G = out_size / 128;

    char* p = (char*)d_ws;
    int* deg_cnt = (int*)p;            p += align256((size_t)N * 4);
    int* row_ptr = (int*)p;            p += align256((size_t)(N + 1) * 4);
    float* dinv = (float*)p;           p += align256((size_t)N * 4);
    int* bsum = (int*)p;               p += align256(64 * 4);
    int* boff = (int*)p;               p += align256(64 * 4);
    int* eidx = (int*)p;               p += align256((size_t)E * 4);
    float* sums = (float*)p;           p += align256(512 * 4);
    float* s_arr = (float*)p;          p += align256(5 * 256 * 4);
    float* sh_arr = (float*)p;         p += align256(5 * 256 * 4);
    float* dvec = (float*)p;           p += align256(256 * 4);
    unsigned short* Wt = (unsigned short*)p; p += align256(256 * 256 * 2);
    float* part = (float*)p;           p += align256((size_t)G * POOL_S * 128 * 4);
    unsigned short* xb = (unsigned short*)p;   p += align256((size_t)N * 128 * 2);
    unsigned short* bufA = (unsigned short*)p; p += align256((size_t)N * 256 * 2);
    unsigned short* bufB = (unsigned short*)p; p += align256((size_t)N * 256 * 2);

    k_cvt<<<(N * 128 / 8 + 255) / 256, 256, 0, stream>>>(x, xb, N * 128 / 8);

    hipMemsetAsync(deg_cnt, 0, (size_t)N * 4, stream);
    k_count<<<(E + 255) / 256, 256, 0, stream>>>(ei, deg_cnt, E);
    k_deg<<<(N + 255) / 256, 256, 0, stream>>>(deg_cnt, dinv, N);
    const int nb = (N + 1023) / 1024;
    k_scan1<<<nb, 256, 0, stream>>>(deg_cnt, bsum, N);
    k_scan2<<<1, 64, 0, stream>>>(bsum, boff, row_ptr, nb, N);
    k_scan3<<<nb, 256, 0, stream>>>(deg_cnt, boff, row_ptr, N);
    hipMemsetAsync(deg_cnt, 0, (size_t)N * 4, stream);
    k_fill<<<(E + 255) / 256, 256, 0, stream>>>(ei, row_ptr, deg_cnt, eidx, E);
    k_init_affine<<<1, 256, 0, stream>>>(s_arr, sh_arr, sums);

    const int ablocks = (N + 3) / 4;
    const int gx = (N + 127) / 128;

    // ---- L1: agg(xb) [N,128] -> mfma 128->256 fused ----
    k_aggw<128, false><<<ablocks, 256, 0, stream>>>(xb, s_arr, sh_arr, nullptr, nullptr,
        row_ptr, eidx, dinv, bufA, N);
    k_prepW<<<(128 * 256 + 255) / 256, 256, 0, stream>>>(Wp[0], nullptr, Wt, 128, 256);
    k_mfma2<128, 256, true><<<dim3(gx, 2), 256, 0, stream>>>(bufA, Wt, bp[0], bufB, sums, N);
    k_finalize<<<1, 256, 0, stream>>>(sums, gp[0], btp[0], s_arr + 256, sh_arr + 256, (float)N);

    // ---- L2, L3 ----
    for (int L = 1; L <= 2; ++L) {
        k_aggw<256, false><<<ablocks, 256, 0, stream>>>(bufB, s_arr + L * 256, sh_arr + L * 256,
            nullptr, nullptr, row_ptr, eidx, dinv, bufA, N);
        k_prepW<<<(256 * 256 + 255) / 256, 256, 0, stream>>>(Wp[L], nullptr, Wt, 256, 256);
        k_mfma2<256, 256, true><<<dim3(gx, 2), 256, 0, stream>>>(bufA, Wt, bp[L], bufB, sums, N);
        k_finalize<<<1, 256, 0, stream>>>(sums, gp[L], btp[L],
                                          s_arr + (L + 1) * 256, sh_arr + (L + 1) * 256, (float)N);
    }

    // ---- L4: GEMM-first (fold s3 into W, sh3 into dvec), then agg in 128 cols ----
    k_prepW<<<(256 * 128 + 255) / 256, 256, 0, stream>>>(Wp[3], s_arr + 3 * 256, Wt, 256, 128);
    k_prepd<<<1, 128, 0, stream>>>(Wp[3], sh_arr + 3 * 256, dvec, 256, 128);
    k_mfma2<256, 128, false><<<dim3(gx, 1), 256, 0, stream>>>(bufB, Wt, nullptr, bufA, nullptr, N);
    k_aggw<128, true><<<ablocks, 256, 0, stream>>>(bufA, nullptr, nullptr, dvec, bp[3],
        row_ptr, eidx, dinv, bufB, N);
    k_stats_bf<<<256, 128, 0, stream>>>(bufB, sums, N);
    k_finalize<<<1, 128, 0, stream>>>(sums, gp[3], btp[3], s_arr + 4 * 256, sh_arr + 4 * 256, (float)N);

    dim3 pgrid(G, POOL_S);
    k_pool1<<<pgrid, 128, 0, stream>>>(bufB, batch, part, N);
    k_pool2<<<G, 128, 0, stream>>>(part, batch, s_arr + 4 * 256, sh_arr + 4 * 256,
                                   (float*)d_out, N);
}

// Round 8
// 510.341 us; speedup vs baseline: 1.2627x; 1.1096x over previous
//
#include <hip/hip_runtime.h>
#include <hip/hip_bf16.h>

#define NEG_SLOPE 0.01f
#define BN_EPS 1e-5f
#define POOL_S 16

typedef __attribute__((ext_vector_type(8))) short short8;
typedef __attribute__((ext_vector_type(4))) float f32x4;

__device__ __forceinline__ float bf2f(unsigned short b) {
    unsigned int u = ((unsigned int)b) << 16;
    float f; __builtin_memcpy(&f, &u, 4); return f;
}
__device__ __forceinline__ unsigned short f2bf(float f) {
    unsigned int u; __builtin_memcpy(&u, &f, 4);
    u = (u + 0x7FFFu + ((u >> 16) & 1u)) >> 16;
    return (unsigned short)u;
}

__device__ __forceinline__ void gload_lds16(const void* g, void* l) {
    __builtin_amdgcn_global_load_lds(
        (const __attribute__((address_space(1))) void*)g,
        (__attribute__((address_space(3))) void*)l, 16, 0, 0);
}

// ---------------- x fp32 -> bf16 ----------------
__global__ void k_cvt(const float* __restrict__ x, unsigned short* __restrict__ xb, int total8) {
    int i = blockIdx.x * blockDim.x + threadIdx.x;
    if (i < total8) {
        float4 a = ((const float4*)x)[i * 2];
        float4 b = ((const float4*)x)[i * 2 + 1];
        short8 o;
        o[0] = (short)f2bf(a.x); o[1] = (short)f2bf(a.y);
        o[2] = (short)f2bf(a.z); o[3] = (short)f2bf(a.w);
        o[4] = (short)f2bf(b.x); o[5] = (short)f2bf(b.y);
        o[6] = (short)f2bf(b.z); o[7] = (short)f2bf(b.w);
        ((short8*)xb)[i] = o;
    }
}

// ---------------- CSR build ----------------
// 4 edges per thread for memory-level parallelism.
__global__ void k_count(const int* __restrict__ ei, int* __restrict__ cnt, int E) {
    int e0 = (blockIdx.x * blockDim.x + threadIdx.x) * 4;
    if (e0 + 3 < E) {
        int4 d = *(const int4*)(ei + E + e0);
        atomicAdd(&cnt[d.x], 1);
        atomicAdd(&cnt[d.y], 1);
        atomicAdd(&cnt[d.z], 1);
        atomicAdd(&cnt[d.w], 1);
    } else {
        for (int e = e0; e < E; ++e) atomicAdd(&cnt[ei[E + e]], 1);
    }
}

__global__ void k_deg(const int* __restrict__ cnt, float* __restrict__ dinv, int N) {
    int n = blockIdx.x * blockDim.x + threadIdx.x;
    if (n < N) dinv[n] = rsqrtf((float)(cnt[n] + 1));
}

// ---- hierarchical exclusive scan ----
__global__ __launch_bounds__(256) void k_scan1(const int* __restrict__ cnt,
                                               int* __restrict__ bsum, int n) {
    int b = blockIdx.x;
    int t = threadIdx.x;
    int base = b * 1024 + t * 4;
    int s = 0;
    #pragma unroll
    for (int i = 0; i < 4; ++i) s += (base + i < n) ? cnt[base + i] : 0;
    #pragma unroll
    for (int off = 1; off < 64; off <<= 1) s += __shfl_xor(s, off, 64);
    __shared__ int ws[4];
    if ((t & 63) == 0) ws[t >> 6] = s;
    __syncthreads();
    if (t == 0) bsum[b] = ws[0] + ws[1] + ws[2] + ws[3];
}

__global__ void k_scan2(const int* __restrict__ bsum, int* __restrict__ boff,
                        int* __restrict__ row_ptr, int nb, int n) {
    int lane = threadIdx.x;    // 64
    int v = (lane < nb) ? bsum[lane] : 0;
    int x = v;
    #pragma unroll
    for (int off = 1; off < 64; off <<= 1) {
        int t = __shfl_up(x, off, 64);
        if (lane >= off) x += t;
    }
    if (lane < nb) boff[lane] = x - v;
    if (lane == 63) row_ptr[n] = x;
}

__global__ __launch_bounds__(256) void k_scan3(const int* __restrict__ cnt,
                                               const int* __restrict__ boff,
                                               int* __restrict__ row_ptr, int n) {
    int b = blockIdx.x;
    int t = threadIdx.x;
    int lane = t & 63, w = t >> 6;
    int base = b * 1024 + t * 4;
    int v[4];
    #pragma unroll
    for (int i = 0; i < 4; ++i) v[i] = (base + i < n) ? cnt[base + i] : 0;
    int tsum = v[0] + v[1] + v[2] + v[3];
    int x = tsum;
    #pragma unroll
    for (int off = 1; off < 64; off <<= 1) {
        int tt = __shfl_up(x, off, 64);
        if (lane >= off) x += tt;
    }
    __shared__ int ws[4];
    if (lane == 63) ws[w] = x;
    __syncthreads();
    int woff = 0;
    for (int k = 0; k < 4; ++k) if (k < w) woff += ws[k];
    int excl = boff[b] + woff + x - tsum;
    #pragma unroll
    for (int i = 0; i < 4; ++i) {
        if (base + i < n) row_ptr[base + i] = excl;
        excl += v[i];
    }
}

// fill via atomicSub on the (now dead) counts: pos = old-1. No second memset.
__global__ void k_fill(const int* __restrict__ ei, const int* __restrict__ row_ptr,
                       int* __restrict__ cnt, int* __restrict__ eidx, int E) {
    int e0 = (blockIdx.x * blockDim.x + threadIdx.x) * 4;
    if (e0 + 3 < E) {
        int4 s = *(const int4*)(ei + e0);
        int4 d = *(const int4*)(ei + E + e0);
        int p0 = atomicSub(&cnt[d.x], 1) - 1;
        int p1 = atomicSub(&cnt[d.y], 1) - 1;
        int p2 = atomicSub(&cnt[d.z], 1) - 1;
        int p3 = atomicSub(&cnt[d.w], 1) - 1;
        eidx[row_ptr[d.x] + p0] = s.x;
        eidx[row_ptr[d.y] + p1] = s.y;
        eidx[row_ptr[d.z] + p2] = s.z;
        eidx[row_ptr[d.w] + p3] = s.w;
    } else {
        for (int e = e0; e < E; ++e) {
            int src = ei[e];
            int dst = ei[E + e];
            int pos = atomicSub(&cnt[dst], 1) - 1;
            eidx[row_ptr[dst] + pos] = src;
        }
    }
}

__global__ void k_init_affine(float* __restrict__ s, float* __restrict__ sh,
                              float* __restrict__ sums) {
    int c = threadIdx.x;
    s[c] = 1.0f;
    sh[c] = 0.0f;
    sums[c] = 0.f;
    sums[256 + c] = 0.f;
}

// ---------------- W prep: Wt[n][k] = (scale?scale[k]:1) * W[k][n], bf16 ----------------
__global__ void k_prepW(const float* __restrict__ W, const float* __restrict__ scale,
                        unsigned short* __restrict__ Wt, int K, int DO) {
    int idx = blockIdx.x * blockDim.x + threadIdx.x;
    if (idx < K * DO) {
        int k = idx / DO, n = idx % DO;
        float v = W[idx];
        if (scale) v *= scale[k];
        Wt[(size_t)n * K + k] = f2bf(v);
    }
}

// d[c] = sum_k sh[k]*W[k][c] — one block per c, thread=k, reduce.
__global__ __launch_bounds__(256) void k_prepd(const float* __restrict__ W,
                                               const float* __restrict__ sh,
                                               float* __restrict__ d, int K, int DO) {
    int c = blockIdx.x;
    int t = threadIdx.x;
    float a = (t < K) ? sh[t] * W[(size_t)t * DO + c] : 0.f;
    #pragma unroll
    for (int off = 1; off < 64; off <<= 1) a += __shfl_xor(a, off, 64);
    __shared__ float ws[4];
    if ((t & 63) == 0) ws[t >> 6] = a;
    __syncthreads();
    if (t == 0) d[c] = ws[0] + ws[1] + ws[2] + ws[3];
}

// ---------------- wave-per-node aggregation, unroll-4, in-register wsum ----
template<int COLS, bool EPI>
__global__ __launch_bounds__(256) void k_aggw(const unsigned short* __restrict__ h,
    const float* __restrict__ s, const float* __restrict__ sh,
    const float* __restrict__ dv, const float* __restrict__ bias,
    const int* __restrict__ row_ptr, const int* __restrict__ eidx,
    const float* __restrict__ dinv, unsigned short* __restrict__ t, int N) {
    constexpr int LPR = COLS / 8;
    constexpr int GR  = 64 / LPR;
    constexpr int SH  = (COLS == 256) ? 8 : 7;
    int n = blockIdx.x * 4 + (threadIdx.x >> 6);
    if (n >= N) return;
    int l = threadIdx.x & 63;
    int ct = l & (LPR - 1);
    int gp = l / LPR;
    const unsigned short* up = h + ct * 8;
    int b = row_ptr[n], e = row_ptr[n + 1];
    int cnt = e - b;
    int per = (cnt + GR - 1) / GR;
    int jb = b + gp * per;
    int je = min(jb + per, e);
    float dn = dinv[n];
    float acc[8] = {};
    float ssum = 0.f;
    if (gp == 0) {
        short8 hv = *(const short8*)(up + ((size_t)n << SH));
        #pragma unroll
        for (int i = 0; i < 8; ++i) acc[i] += dn * bf2f((unsigned short)hv[i]);
    }
    int j = jb;
    for (; j + 4 <= je; j += 4) {
        int s0 = eidx[j], s1 = eidx[j + 1], s2 = eidx[j + 2], s3 = eidx[j + 3];
        float d0 = dinv[s0], d1 = dinv[s1], d2 = dinv[s2], d3 = dinv[s3];
        short8 r0 = *(const short8*)(up + ((size_t)s0 << SH));
        short8 r1 = *(const short8*)(up + ((size_t)s1 << SH));
        short8 r2 = *(const short8*)(up + ((size_t)s2 << SH));
        short8 r3 = *(const short8*)(up + ((size_t)s3 << SH));
        ssum += (d0 + d1) + (d2 + d3);
        #pragma unroll
        for (int i = 0; i < 8; ++i) {
            float a01 = d0 * bf2f((unsigned short)r0[i]) + d1 * bf2f((unsigned short)r1[i]);
            float a23 = d2 * bf2f((unsigned short)r2[i]) + d3 * bf2f((unsigned short)r3[i]);
            acc[i] += a01 + a23;
        }
    }
    for (; j < je; ++j) {
        int s0 = eidx[j];
        float d0 = dinv[s0];
        ssum += d0;
        short8 r0 = *(const short8*)(up + ((size_t)s0 << SH));
        #pragma unroll
        for (int i = 0; i < 8; ++i) acc[i] += d0 * bf2f((unsigned short)r0[i]);
    }
    #pragma unroll
    for (int mask = LPR; mask < 64; mask <<= 1) {
        #pragma unroll
        for (int i = 0; i < 8; ++i) acc[i] += __shfl_xor(acc[i], mask, 64);
        ssum += __shfl_xor(ssum, mask, 64);
    }
    if (gp == 0) {
        float ws = dn * ssum + dn * dn;
        short8 ov;
        #pragma unroll
        for (int i = 0; i < 8; ++i) {
            int col = ct * 8 + i;
            float o;
            if constexpr (EPI) {
                o = dn * acc[i] + ws * dv[col] + bias[col];
                o = o > 0.f ? o : NEG_SLOPE * o;
            } else {
                o = s[col] * (dn * acc[i]) + sh[col] * ws;
            }
            ov[i] = (short)f2bf(o);
        }
        *(short8*)(t + ((size_t)n << SH) + ct * 8) = ov;
    }
}

// ---------------- staged MFMA GEMM (128x128 tile, BK=64, swizzled LDS) -------
template<int K, int DO, bool FUSE>
__global__ __launch_bounds__(256) void k_mfma2(
    const unsigned short* __restrict__ A, const unsigned short* __restrict__ Wt,
    const float* __restrict__ bias, unsigned short* __restrict__ H,
    float* __restrict__ sums, int M) {
    __shared__ unsigned short Asm[128 * 64];
    __shared__ unsigned short Bsm[128 * 64];
    __shared__ float ls[2][128];
    int tid = threadIdx.x;
    int l = tid & 63, w = tid >> 6;
    int wr = w & 1, wc = w >> 1;
    int rl = l & 15, kh = l >> 4;
    int Rb = blockIdx.x * 128;
    int Cb = blockIdx.y * 128;
    int srow = tid >> 3;
    int sd   = tid & 7;
    f32x4 acc[4][4] = {};
    for (int k0 = 0; k0 < K; k0 += 64) {
        #pragma unroll
        for (int i = 0; i < 4; ++i) {
            int row = i * 32 + srow;
            int ss = sd ^ (row & 7);
            int rg = Rb + row; if (rg >= M) rg = M - 1;
            gload_lds16(A + (size_t)rg * K + k0 + ss * 8,
                        (char*)Asm + i * 4096 + w * 1024);
            gload_lds16(Wt + (size_t)(Cb + row) * K + k0 + ss * 8,
                        (char*)Bsm + i * 4096 + w * 1024);
        }
        __syncthreads();
        #pragma unroll
        for (int kk = 0; kk < 2; ++kk) {
            short8 af[4], bf[4];
            #pragma unroll
            for (int mf = 0; mf < 4; ++mf) {
                int r = wr * 64 + mf * 16 + rl;
                int slot = (kk * 4 + kh) ^ (r & 7);
                af[mf] = *(const short8*)((const char*)Asm + r * 128 + slot * 16);
            }
            #pragma unroll
            for (int nf = 0; nf < 4; ++nf) {
                int c = wc * 64 + nf * 16 + rl;
                int slot = (kk * 4 + kh) ^ (c & 7);
                bf[nf] = *(const short8*)((const char*)Bsm + c * 128 + slot * 16);
            }
            #pragma unroll
            for (int mf = 0; mf < 4; ++mf)
                #pragma unroll
                for (int nf = 0; nf < 4; ++nf)
                    acc[mf][nf] = __builtin_amdgcn_mfma_f32_16x16x32_bf16(
                        af[mf], bf[nf], acc[mf][nf], 0, 0, 0);
        }
        __syncthreads();
    }
    if constexpr (FUSE) {
        for (int c = tid; c < 128; c += 256) { ls[0][c] = 0.f; ls[1][c] = 0.f; }
        __syncthreads();
    }
    #pragma unroll
    for (int nf = 0; nf < 4; ++nf) {
        int cl = wc * 64 + nf * 16 + rl;
        int col = Cb + cl;
        float bcol = FUSE ? bias[col] : 0.f;
        float p1 = 0.f, p2 = 0.f;
        #pragma unroll
        for (int mf = 0; mf < 4; ++mf) {
            #pragma unroll
            for (int r = 0; r < 4; ++r) {
                int row = Rb + wr * 64 + mf * 16 + kh * 4 + r;
                if (row < M) {
                    if constexpr (FUSE) {
                        float z = acc[mf][nf][r] + bcol;
                        z = z > 0.f ? z : NEG_SLOPE * z;
                        H[(size_t)row * DO + col] = f2bf(z);
                        p1 += z; p2 += z * z;
                    } else {
                        H[(size_t)row * DO + col] = f2bf(acc[mf][nf][r]);
                    }
                }
            }
        }
        if constexpr (FUSE) {
            atomicAdd(&ls[0][cl], p1);
            atomicAdd(&ls[1][cl], p2);
        }
    }
    if constexpr (FUSE) {
        __syncthreads();
        for (int c = tid; c < 128; c += 256) {
            atomicAdd(&sums[Cb + c], ls[0][c]);
            atomicAdd(&sums[256 + Cb + c], ls[1][c]);
        }
    }
}

// ---------------- BN stats over bf16 [M x 128] ----------------
__global__ void k_stats_bf(const unsigned short* __restrict__ h, float* __restrict__ sums, int M) {
    int c = threadIdx.x;
    float s1 = 0.f, s2 = 0.f;
    for (int r = blockIdx.x; r < M; r += gridDim.x) {
        float v = bf2f(h[(size_t)r * 128 + c]);
        s1 += v; s2 += v * v;
    }
    atomicAdd(&sums[c], s1);
    atomicAdd(&sums[256 + c], s2);
}

// ---------------- BN finalize -> affine (re-zeroes sums) ----------------
__global__ void k_finalize(float* __restrict__ sums, const float* __restrict__ g,
                           const float* __restrict__ bt, float* __restrict__ s_out,
                           float* __restrict__ sh_out, float Nf) {
    int c = threadIdx.x;
    float mu = sums[c] / Nf;
    float var = sums[256 + c] / Nf - mu * mu;
    float rs = rsqrtf(var + BN_EPS);
    float sc = g[c] * rs;
    s_out[c] = sc;
    sh_out[c] = bt[c] - mu * sc;
    sums[c] = 0.f;
    sums[256 + c] = 0.f;
}

// ---------------- global mean pool, two-stage ----------------
__global__ void k_pool1(const unsigned short* __restrict__ h, const int* __restrict__ batch,
                        float* __restrict__ part, int N) {
    int g = blockIdx.x;
    int sidx = blockIdx.y;
    int c = threadIdx.x;
    int lo = 0, hi = N;
    while (lo < hi) { int m = (lo + hi) >> 1; if (batch[m] < g) lo = m + 1; else hi = m; }
    int start = lo; hi = N;
    while (lo < hi) { int m = (lo + hi) >> 1; if (batch[m] < g + 1) lo = m + 1; else hi = m; }
    int end = lo;
    float acc = 0.f;
    for (int r = start + sidx; r < end; r += POOL_S)
        acc += bf2f(h[(size_t)r * 128 + c]);
    part[((size_t)g * POOL_S + sidx) * 128 + c] = acc;
}

__global__ void k_pool2(const float* __restrict__ part, const int* __restrict__ batch,
                        const float* __restrict__ s, const float* __restrict__ sh,
                        float* __restrict__ out, int N) {
    int g = blockIdx.x;
    int c = threadIdx.x;
    int lo = 0, hi = N;
    while (lo < hi) { int m = (lo + hi) >> 1; if (batch[m] < g) lo = m + 1; else hi = m; }
    int start = lo; hi = N;
    while (lo < hi) { int m = (lo + hi) >> 1; if (batch[m] < g + 1) lo = m + 1; else hi = m; }
    int cnt = lo - start;
    float acc = 0.f;
    #pragma unroll
    for (int i = 0; i < POOL_S; ++i) acc += part[((size_t)g * POOL_S + i) * 128 + c];
    out[(size_t)g * 128 + c] = (cnt > 0) ? (s[c] * acc / (float)cnt + sh[c]) : 0.f;
}

// ---------------- host ----------------

static inline size_t align256(size_t x) { return (x + 255) & ~(size_t)255; }

extern "C" void kernel_launch(void* const* d_in, const int* in_sizes, int n_in,
                              void* d_out, int out_size, void* d_ws, size_t ws_size,
                              hipStream_t stream) {
    const float* x   = (const float*)d_in[0];
    const int* ei    = (const int*)d_in[1];
    const int* batch = (const int*)d_in[2];
    const float* Wp[4]  = {(const float*)d_in[3], (const float*)d_in[7],
                           (const float*)d_in[11], (const float*)d_in[15]};
    const float* bp[4]  = {(const float*)d_in[4], (const float*)d_in[8],
                           (const float*)d_in[12], (const float*)d_in[16]};
    const float* gp[4]  = {(const float*)d_in[5], (const float*)d_in[9],
                           (const float*)d_in[13], (const float*)d_in[17]};
    const float* btp[4] = {(const float*)d_in[6], (const float*)d_in[10],
                           (const float*)d_in[14], (const float*)d_in[18]};

    const int N = in_sizes[0] / 128;
    const int E = in_sizes[1] / 2;
    const int G = out_size / 128;

    char* p = (char*)d_ws;
    int* deg_cnt = (int*)p;            p += align256((size_t)N * 4);
    int* row_ptr = (int*)p;            p += align256((size_t)(N + 1) * 4);
    float* dinv = (float*)p;           p += align256((size_t)N * 4);
    int* bsum = (int*)p;               p += align256(64 * 4);
    int* boff = (int*)p;               p += align256(64 * 4);
    int* eidx = (int*)p;               p += align256((size_t)E * 4);
    float* sums = (float*)p;           p += align256(512 * 4);
    float* s_arr = (float*)p;          p += align256(5 * 256 * 4);
    float* sh_arr = (float*)p;         p += align256(5 * 256 * 4);
    float* dvec = (float*)p;           p += align256(256 * 4);
    unsigned short* Wt = (unsigned short*)p; p += align256(256 * 256 * 2);
    float* part = (float*)p;           p += align256((size_t)G * POOL_S * 128 * 4);
    unsigned short* xb = (unsigned short*)p;   p += align256((size_t)N * 128 * 2);
    unsigned short* bufA = (unsigned short*)p; p += align256((size_t)N * 256 * 2);
    unsigned short* bufB = (unsigned short*)p; p += align256((size_t)N * 256 * 2);

    k_cvt<<<(N * 128 / 8 + 255) / 256, 256, 0, stream>>>(x, xb, N * 128 / 8);

    hipMemsetAsync(deg_cnt, 0, (size_t)N * 4, stream);
    k_count<<<(E / 4 + 255) / 256, 256, 0, stream>>>(ei, deg_cnt, E);
    k_deg<<<(N + 255) / 256, 256, 0, stream>>>(deg_cnt, dinv, N);
    const int nb = (N + 1023) / 1024;
    k_scan1<<<nb, 256, 0, stream>>>(deg_cnt, bsum, N);
    k_scan2<<<1, 64, 0, stream>>>(bsum, boff, row_ptr, nb, N);
    k_scan3<<<nb, 256, 0, stream>>>(deg_cnt, boff, row_ptr, N);
    k_fill<<<(E / 4 + 255) / 256, 256, 0, stream>>>(ei, row_ptr, deg_cnt, eidx, E);
    k_init_affine<<<1, 256, 0, stream>>>(s_arr, sh_arr, sums);

    const int ablocks = (N + 3) / 4;
    const int gx = (N + 127) / 128;

    // ---- L1: agg(xb) [N,128] -> mfma 128->256 fused ----
    k_aggw<128, false><<<ablocks, 256, 0, stream>>>(xb, s_arr, sh_arr, nullptr, nullptr,
        row_ptr, eidx, dinv, bufA, N);
    k_prepW<<<(128 * 256 + 255) / 256, 256, 0, stream>>>(Wp[0], nullptr, Wt, 128, 256);
    k_mfma2<128, 256, true><<<dim3(gx, 2), 256, 0, stream>>>(bufA, Wt, bp[0], bufB, sums, N);
    k_finalize<<<1, 256, 0, stream>>>(sums, gp[0], btp[0], s_arr + 256, sh_arr + 256, (float)N);

    // ---- L2, L3 ----
    for (int L = 1; L <= 2; ++L) {
        k_aggw<256, false><<<ablocks, 256, 0, stream>>>(bufB, s_arr + L * 256, sh_arr + L * 256,
            nullptr, nullptr, row_ptr, eidx, dinv, bufA, N);
        k_prepW<<<(256 * 256 + 255) / 256, 256, 0, stream>>>(Wp[L], nullptr, Wt, 256, 256);
        k_mfma2<256, 256, true><<<dim3(gx, 2), 256, 0, stream>>>(bufA, Wt, bp[L], bufB, sums, N);
        k_finalize<<<1, 256, 0, stream>>>(sums, gp[L], btp[L],
                                          s_arr + (L + 1) * 256, sh_arr + (L + 1) * 256, (float)N);
    }

    // ---- L4: GEMM-first (fold s3 into W, sh3 into dvec), then agg in 128 cols ----
    k_prepW<<<(256 * 128 + 255) / 256, 256, 0, stream>>>(Wp[3], s_arr + 3 * 256, Wt, 256, 128);
    k_prepd<<<128, 256, 0, stream>>>(Wp[3], sh_arr + 3 * 256, dvec, 256, 128);
    k_mfma2<256, 128, false><<<dim3(gx, 1), 256, 0, stream>>>(bufB, Wt, nullptr, bufA, nullptr, N);
    k_aggw<128, true><<<ablocks, 256, 0, stream>>>(bufA, nullptr, nullptr, dvec, bp[3],
        row_ptr, eidx, dinv, bufB, N);
    k_stats_bf<<<256, 128, 0, stream>>>(bufB, sums, N);
    k_finalize<<<1, 128, 0, stream>>>(sums, gp[3], btp[3], s_arr + 4 * 256, sh_arr + 4 * 256, (float)N);

    dim3 pgrid(G, POOL_S);
    k_pool1<<<pgrid, 128, 0, stream>>>(bufB, batch, part, N);
    k_pool2<<<G, 128, 0, stream>>>(part, batch, s_arr + 4 * 256, sh_arr + 4 * 256,
                                   (float*)d_out, N);
}